// Round 3
// baseline (36.173 us; speedup 1.0000x reference)
//
#include <hip/hip_runtime.h>
#include <math.h>

// DeepFeatureLoss: B=2, N=4096, D=32, fp32 in/out.
// out[0..1] = ce_loss[b], out[2..3] = reg_loss[b].
//
// ce_i = log(s_f) - t/s_p   (softmax max pinned at 0; both dists <= 0):
//   s_p = sum_j exp(pd_ij), t = sum_j exp(pd_ij)*fd_ij, s_f = sum_j exp(fd_ij)
//
// exp2 folding: all exponents kept in log2 units so each exp is a bare
// v_exp_f32:  points pre-scaled by 200*sqrt(log2e)  -> pd' = log2e*pd
//             features pre-scaled by sqrt(2*log2e)  -> mfma dot = log2e*(2 dot)
//             norms stored * log2e                  -> fd' = dot'' - n1' - n2'
//   t' = sum ep*fd' = log2e * t  -> multiply by ln2 in k2.
//
// Fragment layouts (mfma_f32_16x16x32_f16, verified R2):
//   A[row][k]: row = lane&15, k = (lane>>4)*8 + i
//   B[k][col]: col = lane&15, k = (lane>>4)*8 + i
//   C[row][col]: col = lane&15, row = (lane>>4)*4 + reg
//
// ws (floats): pp1 [0,32768) ; pp2 [32768,65536) ; f2 f16 frags
// [65536,196608) ; partials [196608, 196608+16*3*8192).  ~2.3 MB.

#define NPTS 4096
#define BATCH 2
#define DF 32
#define ROWS_TOT (BATCH * NPTS)   // 8192
#define NCHUNK 16                  // j-chunks of 256 (16 j-tiles each)

#define L2E  1.4426950408889634f
#define LN2  0.6931471805599453f
#define FSC  1.6986436f            // sqrt(2*log2e)
#define PSC  240.2244f             // 200*sqrt(log2e)

typedef _Float16 half8 __attribute__((ext_vector_type(8)));
typedef float f4 __attribute__((ext_vector_type(4)));

// ---- k0: pack pp1=(p*PSC,n1*L2E), pp2=(p*PSC,n2*L2E), f2*FSC -> f16 frags --
__global__ void k0_prep(const float* __restrict__ pts,
                        const float* __restrict__ f1g,
                        const float* __restrict__ f2g,
                        float* __restrict__ pp1, float* __restrict__ pp2,
                        _Float16* __restrict__ frag, float* __restrict__ out) {
    const int r = blockIdx.x * 64 + threadIdx.x;     // global row 0..8191
    if (r < 4) out[r] = 0.0f;
    const int b = r >> 12, local = r & (NPTS - 1);
    const int jt = (b << 8) + (local >> 4);          // global j-tile id
    const int c  = local & 15;                       // col within tile

    const float4* f2v = (const float4*)(f2g + (size_t)r * DF);
    float vals[32];
    float n2 = 0.0f;
#pragma unroll
    for (int q = 0; q < 8; ++q) {
        float4 v = f2v[q];
        vals[4*q] = v.x; vals[4*q+1] = v.y; vals[4*q+2] = v.z; vals[4*q+3] = v.w;
        n2 += v.x*v.x + v.y*v.y + v.z*v.z + v.w*v.w;
    }
    half8* fv = (half8*)frag;
#pragma unroll
    for (int kb = 0; kb < 4; ++kb) {                 // slot = c*4 + kb
        half8 h;
#pragma unroll
        for (int i = 0; i < 8; ++i) h[i] = (_Float16)(vals[kb*8 + i] * FSC);
        fv[(size_t)jt*64 + c*4 + kb] = h;
    }
    const float4* f1v = (const float4*)(f1g + (size_t)r * DF);
    float n1 = 0.0f;
#pragma unroll
    for (int q = 0; q < 8; ++q) {
        float4 v = f1v[q];
        n1 += v.x*v.x + v.y*v.y + v.z*v.z + v.w*v.w;
    }
    const float* pp = pts + (size_t)r * 3;
    const float px = pp[0]*PSC, py = pp[1]*PSC, pz = pp[2]*PSC;
    ((float4*)pp1)[r] = make_float4(px, py, pz, n1 * L2E);
    ((float4*)pp2)[r] = make_float4(px, py, pz, n2 * L2E);
}

// ---- k1: MFMA dots + fused softmax-sum epilogue (packed-f32 friendly) ----
__launch_bounds__(256)
__global__ void k1_main(const float* __restrict__ f1g,
                        const float* __restrict__ pp1,
                        const float* __restrict__ pp2,
                        const _Float16* __restrict__ frag,
                        float* __restrict__ part) {
    const int tid = threadIdx.x;
    const int l = tid & 63, wv = tid >> 6;
    const int chunk = blockIdx.x & 15;               // 4 waves share chunk (L1 reuse)
    const int i_tile = (blockIdx.x >> 4) * 4 + wv;   // 0..511
    const int b = i_tile >> 8;
    const int i0g = b * NPTS + (i_tile & 255) * 16;  // global row base of tile
    const int lr = l & 15, lk = l >> 4;

    // A fragment: f1[i0g+lr][lk*8 .. +7] * FSC -> f16
    const float* arow = f1g + (size_t)(i0g + lr) * DF + lk * 8;
    const float4 a0 = *(const float4*)arow;
    const float4 a1 = *(const float4*)(arow + 4);
    half8 afrag;
    afrag[0]=(_Float16)(a0.x*FSC); afrag[1]=(_Float16)(a0.y*FSC);
    afrag[2]=(_Float16)(a0.z*FSC); afrag[3]=(_Float16)(a0.w*FSC);
    afrag[4]=(_Float16)(a1.x*FSC); afrag[5]=(_Float16)(a1.y*FSC);
    afrag[6]=(_Float16)(a1.z*FSC); afrag[7]=(_Float16)(a1.w*FSC);

    // this lane's 4 output rows: i0g + lk*4 + r2 ; split coords across-r2
    const int rbase = i0g + lk * 4;
    const float4 q0 = ((const float4*)pp1)[rbase + 0];
    const float4 q1 = ((const float4*)pp1)[rbase + 1];
    const float4 q2 = ((const float4*)pp1)[rbase + 2];
    const float4 q3 = ((const float4*)pp1)[rbase + 3];
    const f4 qx = {q0.x, q1.x, q2.x, q3.x};
    const f4 qy = {q0.y, q1.y, q2.y, q3.y};
    const f4 qz = {q0.z, q1.z, q2.z, q3.z};
    const f4 qw = {q0.w, q1.w, q2.w, q3.w};

    f4 sp = {0,0,0,0}, tA = {0,0,0,0}, sf = {0,0,0,0};
    const half8* fragv = (const half8*)frag;
    const int jt0 = b * 256 + chunk * 16;
    const int j0g0 = b * NPTS + chunk * 256 + lr;
    const f4 zero = {0.f, 0.f, 0.f, 0.f};

#pragma unroll 4
    for (int t = 0; t < 16; ++t) {
        const half8 bfrag = fragv[(size_t)(jt0 + t) * 64 + lr * 4 + lk];
        const float4 pw = ((const float4*)pp2)[j0g0 + t * 16];
        const f4 cc = __builtin_amdgcn_mfma_f32_16x16x32_f16(afrag, bfrag, zero, 0, 0, 0);
        const f4 fd = cc - (qw + pw.w);        // log2e * fea_dist2 (<=0)
        const f4 dx = qx - pw.x;
        const f4 dy = qy - pw.y;
        const f4 dz = qz - pw.z;
        const f4 s  = dx*dx + dy*dy + dz*dz;   // log2e * |dp|^2
        f4 ep, ef;
#pragma unroll
        for (int e = 0; e < 4; ++e) {
            ep[e] = __builtin_amdgcn_exp2f(-s[e]);
            ef[e] = __builtin_amdgcn_exp2f(fd[e]);
        }
        sp += ep;
        tA += ep * fd;
        sf += ef;
    }

    // reduce over the 16 columns (lane bits 0..3)
#pragma unroll
    for (int m = 1; m < 16; m <<= 1) {
#pragma unroll
        for (int e = 0; e < 4; ++e) {
            sp[e] += __shfl_xor(sp[e], m);
            tA[e] += __shfl_xor(tA[e], m);
            sf[e] += __shfl_xor(sf[e], m);
        }
    }
    if (lr == 0) {
        float* P = part + (size_t)chunk * 3 * ROWS_TOT;
        *(float4*)(P + rbase)                = make_float4(sp[0], sp[1], sp[2], sp[3]);
        *(float4*)(P + ROWS_TOT + rbase)     = make_float4(tA[0], tA[1], tA[2], tA[3]);
        *(float4*)(P + 2 * ROWS_TOT + rbase) = make_float4(sf[0], sf[1], sf[2], sf[3]);
    }
}

// ---- k2: combine chunk partials, ce + reg reduction ----
__global__ void k2_final(const float* __restrict__ part,
                         const float* __restrict__ f1g,
                         const float* __restrict__ f2g,
                         const float* __restrict__ wg,
                         float* __restrict__ out) {
    const int tid = threadIdx.x;
    const int r = blockIdx.x * 64 + tid;
    const int b = r >> 12;

    float sp = 0.f, tp = 0.f, sf = 0.f;
#pragma unroll 4
    for (int c = 0; c < NCHUNK; ++c) {
        const float* P = part + (size_t)c * 3 * ROWS_TOT;
        sp += P[r];
        tp += P[ROWS_TOT + r];
        sf += P[2 * ROWS_TOT + r];
    }
    const float ce = logf(sf) - (tp * LN2) / sp;   // un-scale t by ln2
    float contrib = wg[r] * ce;

    const float4* a4 = (const float4*)(f1g + (size_t)r * DF);
    const float4* b4 = (const float4*)(f2g + (size_t)r * DF);
    float rr;
    {
        float4 a0 = a4[0], b0 = b4[0];
        rr = a0.w * a0.w + b0.w * b0.w;   // channel 3 from first quad
    }
#pragma unroll
    for (int q = 1; q < 8; ++q) {
        float4 av = a4[q], bv = b4[q];
        rr += av.x*av.x + av.y*av.y + av.z*av.z + av.w*av.w;
        rr += bv.x*bv.x + bv.y*bv.y + bv.z*bv.z + bv.w*bv.w;
    }

#pragma unroll
    for (int off = 32; off > 0; off >>= 1) {
        contrib += __shfl_down(contrib, off);
        rr      += __shfl_down(rr, off);
    }
    if (tid == 0) {
        atomicAdd(&out[b],     contrib);
        atomicAdd(&out[2 + b], rr * (1.0f / (29.0f * (float)NPTS)));
    }
}

extern "C" void kernel_launch(void* const* d_in, const int* in_sizes, int n_in,
                              void* d_out, int out_size, void* d_ws, size_t ws_size,
                              hipStream_t stream) {
    const float* pts = (const float*)d_in[0];
    const float* f1  = (const float*)d_in[1];
    const float* f2  = (const float*)d_in[2];
    const float* wg  = (const float*)d_in[3];
    float* out = (float*)d_out;

    float* ws = (float*)d_ws;
    float*     pp1  = ws;                       // 32768 floats
    float*     pp2  = ws + 32768;               // 32768 floats
    _Float16*  frag = (_Float16*)(ws + 65536);  // 262144 halves (131072 floats)
    float*     part = ws + 196608;              // 16*3*8192 floats

    k0_prep<<<ROWS_TOT / 64, 64, 0, stream>>>(pts, f1, f2, pp1, pp2, frag, out);
    k1_main<<<dim3((ROWS_TOT / 16 / 4) * NCHUNK), 256, 0, stream>>>(f1, pp1, pp2, frag, part);
    k2_final<<<ROWS_TOT / 64, 64, 0, stream>>>(part, f1, f2, wg, out);
}